// Round 14
// baseline (221.703 us; speedup 1.0000x reference)
//
#include <hip/hip_runtime.h>
#include <hip/hip_bf16.h>
#include <cstdint>

#define QMAXF 127.0f
#define EPSQ 1e-8f

typedef __bf16 bf16x8 __attribute__((ext_vector_type(8)));
typedef float f32x4 __attribute__((ext_vector_type(4)));

static constexpr int BB = 32;   // 2*16 batch
static constexpr int MM = 2048;
static constexpr int KK = 128;
static constexpr int NN = 2048;

// workspace layout (bytes)
static constexpr size_t OFF_Q1   = 0;                                  // ushort rows of A (int-valued bf16, K-swizzled)
static constexpr size_t OFF_Q2T  = OFF_Q1  + (size_t)BB*MM*KK*2;       // ushort rows of B^T (dequant bf16, K-swizzled)
static constexpr size_t OFF_S1   = OFF_Q2T + (size_t)BB*NN*KK*2;       // float[B*M]
static constexpr size_t OFF_S2   = OFF_S1  + (size_t)BB*MM*4;          // float[B*K]

// ---------------- quantize inputs1: per-row (K=128) amax; store exact-int bf16, K-swizzled ----------------
__global__ __launch_bounds__(256) void quant_rows128(const float* __restrict__ x,
                                                     unsigned short* __restrict__ q,
                                                     float* __restrict__ s1) {
    int wave = threadIdx.x >> 6, lane = threadIdx.x & 63;
    int row = blockIdx.x * 4 + wave;               // 65536 rows
    const float2* xr = reinterpret_cast<const float2*>(x) + (size_t)row * 64;
    float2 v = xr[lane];
    float a = fmaxf(fabsf(v.x), fabsf(v.y));
#pragma unroll
    for (int m = 32; m; m >>= 1) a = fmaxf(a, __shfl_xor(a, m));
    float scale = fmaxf(a, EPSQ) / QMAXF;
    float i0 = fminf(fmaxf(rintf(v.x / scale), -128.f), 127.f);
    float i1 = fminf(fmaxf(rintf(v.y / scale), -128.f), 127.f);
    __bf16 h0 = (__bf16)i0, h1 = (__bf16)i1;       // integers <=128: exact in bf16
    ushort2 st;
    st.x = *reinterpret_cast<unsigned short*>(&h0);
    st.y = *reinterpret_cast<unsigned short*>(&h1);
    // swizzle: ushort idx (2*lane) ^ ((row&7)<<3)  ->  ushort2 idx lane ^ ((row&7)<<2)
    reinterpret_cast<ushort2*>(q + (size_t)row * 128)[lane ^ ((row & 7) << 2)] = st;
    if (lane == 0) s1[row] = scale;
}

// ---------------- inputs2: per-k-row (N=2048) amax -> s2 ----------------
__global__ __launch_bounds__(256) void amax_rows2048(const float* __restrict__ x,
                                                     float* __restrict__ s2) {
    int row = blockIdx.x;                          // B*K = 4096 rows
    const float4* xr = reinterpret_cast<const float4*>(x) + (size_t)row * 512;
    int t = threadIdx.x;
    float4 v0 = xr[t], v1 = xr[t + 256];
    float a = fmaxf(fmaxf(fmaxf(fabsf(v0.x), fabsf(v0.y)), fmaxf(fabsf(v0.z), fabsf(v0.w))),
                    fmaxf(fmaxf(fabsf(v1.x), fabsf(v1.y)), fmaxf(fabsf(v1.z), fabsf(v1.w))));
#pragma unroll
    for (int m = 32; m; m >>= 1) a = fmaxf(a, __shfl_xor(a, m));
    __shared__ float red[4];
    if ((t & 63) == 0) red[t >> 6] = a;
    __syncthreads();
    if (t == 0) {
        float m0 = fmaxf(fmaxf(red[0], red[1]), fmaxf(red[2], red[3]));
        s2[row] = fmaxf(m0, EPSQ) / QMAXF;
    }
}

// ---------------- inputs2: dequantize + transpose to q2t [b][n][k^swz] ----------------
__global__ __launch_bounds__(256) void quant_transpose(const float* __restrict__ x,
                                                       const float* __restrict__ s2,
                                                       unsigned short* __restrict__ q2t) {
    int b = blockIdx.x >> 5;
    int n0 = (blockIdx.x & 31) * 64;
    __shared__ unsigned short lds[64][136];
    int t = threadIdx.x;
    int rr = t >> 4, cc = t & 15;
#pragma unroll
    for (int p = 0; p < 8; ++p) {
        int k = p * 16 + rr;
        float s = s2[b * 128 + k];
        const float4* src = reinterpret_cast<const float4*>(x + ((size_t)b * 128 + k) * 2048 + n0);
        float4 v = src[cc];
        float f[4] = {v.x, v.y, v.z, v.w};
#pragma unroll
        for (int e = 0; e < 4; ++e) {
            float iq = fminf(fmaxf(rintf(f[e] / s), -128.f), 127.f);
            __bf16 h = (__bf16)(iq * s);
            lds[cc * 4 + e][k] = *reinterpret_cast<unsigned short*>(&h);
        }
    }
    __syncthreads();
    int nl = t >> 2, seg = t & 3;
    int sw = nl & 7;                               // (n0+nl)&7 == nl&7 (n0 multiple of 64)
    uint4* dstrow = reinterpret_cast<uint4*>(q2t + ((size_t)b * 2048 + n0 + nl) * 128);
#pragma unroll
    for (int j = 0; j < 4; ++j)
        dstrow[(seg * 4 + j) ^ sw] = *reinterpret_cast<const uint4*>(&lds[nl][seg * 32 + j * 8]);
}

// ---------------- fused GEMM: one block per (b, 64-row M-half-panel). 1024 blocks = 4/CU.
// A frags: global -> registers in prologue (no LDS). B tiles (64N x 128K = 16 KB)
// double-buffered in LDS via global_load_lds. MFMA operands swapped (R10-verified):
// lane owns row=lr, 4 consecutive cols. Sweep 1 (it 0..31): deferred per-lane amax.
// Sweep 2 (it 32..63): recompute + quantize + float4 store, vmcnt(4) counted drain. ----------------
__global__ __launch_bounds__(256, 4) void gemm_fused(const unsigned short* __restrict__ qa,
                                                     const unsigned short* __restrict__ qbt,
                                                     const float* __restrict__ s1,
                                                     float* __restrict__ out) {
    int id = blockIdx.x;
    int nid = (id & 7) * 128 + (id >> 3);          // XCD-chunked, bijective for 1024 blocks
    int b = nid >> 5, mh = nid & 31;               // mh: 64-row M-half-panel index
    int m0 = mh * 64;

    __shared__ unsigned short Bt[2][8192];         // 2 x 16 KB B double-buffer
    __shared__ float rowAmax[64], sOsc[64], sQs[64], sS1[64];

    int tid = threadIdx.x, wave = tid >> 6, lane = tid & 63;
    if (tid < 64) {
        rowAmax[tid] = 0.f;
        sS1[tid] = s1[b * 2048 + m0 + tid];
    }

    int wm = wave >> 1, wn = wave & 1;             // 2x2 waves, 32x32 output each
    int lr = lane & 15, lg = lane >> 4;
    int swz = (lr & 7) << 3;                       // XOR swizzle (matches image layout)

    {   // stage B0 into Bt[0]
        const char* Bg = (const char*)(qbt + (size_t)b * 2048 * 128);
#pragma unroll
        for (int i = 0; i < 4; ++i) {
            int off = i * 4096 + wave * 1024;      // wave-uniform LDS dest; HW adds lane*16
            __builtin_amdgcn_global_load_lds(
                (const __attribute__((address_space(1))) uint32_t*)(Bg + off + lane * 16),
                (__attribute__((address_space(3))) uint32_t*)((char*)&Bt[0][0] + off), 16, 0, 0);
        }
    }

    // A fragments: straight global -> registers (8 KB per wave, one-time, mostly L2)
    bf16x8 afr[4][2];
    {
        const unsigned short* Ai = qa + (size_t)(b * 2048 + m0) * 128;
#pragma unroll
        for (int ks = 0; ks < 4; ++ks)
#pragma unroll
            for (int mi = 0; mi < 2; ++mi)
                afr[ks][mi] = *reinterpret_cast<const bf16x8*>(
                    &Ai[(wm * 32 + mi * 16 + lr) * 128 + ((ks * 32 + lg * 8) ^ swz)]);
    }
    __syncthreads();                               // B0 landed

    size_t ob = (size_t)b * 2048 * 2048;
    float rmax[2] = {0.f, 0.f};                    // per-lane running |C| max, one per mi

    for (int it = 0; it < 64; ++it) {
        int cur = it & 1;                          // Bt[cur] holds B tile (it & 31)
        if (it < 63) {                             // prefetch next B tile (ISSUED FIRST)
            int nnt = (it + 1) & 31;
            const char* Bg = (const char*)(qbt + (size_t)(b * 2048 + nnt * 64) * 128);
            char* lB = (char*)&Bt[cur ^ 1][0];
#pragma unroll
            for (int i = 0; i < 4; ++i) {
                int off = i * 4096 + wave * 1024;
                __builtin_amdgcn_global_load_lds(
                    (const __attribute__((address_space(1))) uint32_t*)(Bg + off + lane * 16),
                    (__attribute__((address_space(3))) uint32_t*)(lB + off), 16, 0, 0);
            }
        }
        // pin issue order: prefetch loads must precede this iteration's stores
        __builtin_amdgcn_sched_barrier(0);

        if (it == 32) {                            // sweep boundary: row amax complete
            if (tid < 64) {
                float am = rowAmax[tid] * sS1[tid];
                float osc = fmaxf(am, EPSQ) / QMAXF;
                sOsc[tid] = osc;
                sQs[tid] = sS1[tid] / osc;         // folded (raw_acc * s1) / osc
            }
            __syncthreads();
        }

        f32x4 acc[2][2];
#pragma unroll
        for (int mi = 0; mi < 2; ++mi)
#pragma unroll
            for (int ni = 0; ni < 2; ++ni) {
                f32x4 z = {0.f, 0.f, 0.f, 0.f};
                acc[mi][ni] = z;
            }

#pragma unroll
        for (int ks = 0; ks < 4; ++ks) {
            int kb = (ks * 32 + lg * 8) ^ swz;
            bf16x8 bfr[2];
#pragma unroll
            for (int ni = 0; ni < 2; ++ni)
                bfr[ni] = *reinterpret_cast<const bf16x8*>(&Bt[cur][(wn * 32 + ni * 16 + lr) * 128 + kb]);
            // SWAPPED operands (R10-verified): lane holds row=lr, cols=lg*4+r per ni
#pragma unroll
            for (int mi = 0; mi < 2; ++mi)
#pragma unroll
                for (int ni = 0; ni < 2; ++ni)
                    acc[mi][ni] = __builtin_amdgcn_mfma_f32_16x16x32_bf16(bfr[ni], afr[ks][mi], acc[mi][ni], 0, 0, 0);
        }

        if (it < 32) {
            // sweep 1: deferred amax — per-lane running max only (no shuffles, no atomics)
#pragma unroll
            for (int mi = 0; mi < 2; ++mi)
#pragma unroll
                for (int ni = 0; ni < 2; ++ni)
#pragma unroll
                    for (int r = 0; r < 4; ++r)
                        rmax[mi] = fmaxf(rmax[mi], fabsf(acc[mi][ni][r]));
            if (it == 31) {                        // one-time cross-lane reduce (over lg groups)
#pragma unroll
                for (int mi = 0; mi < 2; ++mi) {
                    float v = rmax[mi];
                    v = fmaxf(v, __shfl_xor(v, 16));
                    v = fmaxf(v, __shfl_xor(v, 32));
                    if (lg == 0) {                 // raw amax >=0: uint compare == float compare
                        int row = wm * 32 + mi * 16 + lr;
                        atomicMax(reinterpret_cast<unsigned*>(&rowAmax[row]), __float_as_uint(v));
                    }
                }
            }
            __syncthreads();                       // full drain: next tile landed, reads done
        } else {
            // sweep 2: quantize + plain float4 store
            int nt = it & 31;
#pragma unroll
            for (int mi = 0; mi < 2; ++mi) {
                int row = wm * 32 + mi * 16 + lr;
                float qs = sQs[row], osc = sOsc[row];
                size_t rowoff = ob + (size_t)(m0 + row) * 2048 + nt * 64 + wn * 32 + lg * 4;
#pragma unroll
                for (int ni = 0; ni < 2; ++ni) {
                    f32x4 qv;
                    qv[0] = fminf(fmaxf(rintf(acc[mi][ni][0] * qs), -128.f), 127.f) * osc;
                    qv[1] = fminf(fmaxf(rintf(acc[mi][ni][1] * qs), -128.f), 127.f) * osc;
                    qv[2] = fminf(fmaxf(rintf(acc[mi][ni][2] * qs), -128.f), 127.f) * osc;
                    qv[3] = fminf(fmaxf(rintf(acc[mi][ni][3] * qs), -128.f), 127.f) * osc;
                    *reinterpret_cast<f32x4*>(&out[rowoff + ni * 16]) = qv;
                }
            }
            // counted drain: 8 VMEM in flight (4 loads issued first + 4 float4 stores).
            // vmcnt(4) retires the 4 oldest = all loads; stores drain across next iter's MFMA.
            asm volatile("s_waitcnt vmcnt(4) lgkmcnt(0)" ::: "memory");
            __builtin_amdgcn_s_barrier();
        }
    }
}

extern "C" void kernel_launch(void* const* d_in, const int* in_sizes, int n_in,
                              void* d_out, int out_size, void* d_ws, size_t ws_size,
                              hipStream_t stream) {
    const float* in1 = (const float*)d_in[0];  // [2,16,2048,128]
    const float* in2 = (const float*)d_in[1];  // [2,16,128,2048]
    char* ws = (char*)d_ws;
    unsigned short* q1  = (unsigned short*)(ws + OFF_Q1);
    unsigned short* q2t = (unsigned short*)(ws + OFF_Q2T);
    float* s1   = (float*)(ws + OFF_S1);
    float* s2   = (float*)(ws + OFF_S2);
    float* out  = (float*)d_out;

    quant_rows128 <<<BB * MM / 4, 256, 0, stream>>>(in1, q1, s1);
    amax_rows2048 <<<BB * KK,     256, 0, stream>>>(in2, s2);
    quant_transpose<<<BB * (NN / 64), 256, 0, stream>>>(in2, s2, q2t);
    gemm_fused    <<<BB * 32,     256, 0, stream>>>(q1, q2t, s1, out);  // 1024 blocks = 1 per 64-row half-panel
}

// Round 15
// 220.768 us; speedup vs baseline: 1.0042x; 1.0042x over previous
//
#include <hip/hip_runtime.h>
#include <hip/hip_bf16.h>
#include <cstdint>

#define QMAXF 127.0f
#define EPSQ 1e-8f

typedef __bf16 bf16x8 __attribute__((ext_vector_type(8)));
typedef float f32x4 __attribute__((ext_vector_type(4)));

static constexpr int BB = 32;   // 2*16 batch
static constexpr int MM = 2048;
static constexpr int KK = 128;
static constexpr int NN = 2048;

// workspace layout (bytes)
static constexpr size_t OFF_Q1   = 0;                                  // ushort tile-images of A (swizzled)
static constexpr size_t OFF_Q2T  = OFF_Q1  + (size_t)BB*MM*KK*2;       // ushort tile-images of B^T (swizzled)
static constexpr size_t OFF_S1   = OFF_Q2T + (size_t)BB*NN*KK*2;       // float[B*M]
static constexpr size_t OFF_S2   = OFF_S1  + (size_t)BB*MM*4;          // float[B*K]

// ---------------- quantize inputs1: per-row (K=128) amax; store exact-int bf16, K-swizzled ----------------
__global__ __launch_bounds__(256) void quant_rows128(const float* __restrict__ x,
                                                     unsigned short* __restrict__ q,
                                                     float* __restrict__ s1) {
    int wave = threadIdx.x >> 6, lane = threadIdx.x & 63;
    int row = blockIdx.x * 4 + wave;               // 65536 rows
    const float2* xr = reinterpret_cast<const float2*>(x) + (size_t)row * 64;
    float2 v = xr[lane];
    float a = fmaxf(fabsf(v.x), fabsf(v.y));
#pragma unroll
    for (int m = 32; m; m >>= 1) a = fmaxf(a, __shfl_xor(a, m));
    float scale = fmaxf(a, EPSQ) / QMAXF;
    float i0 = fminf(fmaxf(rintf(v.x / scale), -128.f), 127.f);
    float i1 = fminf(fmaxf(rintf(v.y / scale), -128.f), 127.f);
    __bf16 h0 = (__bf16)i0, h1 = (__bf16)i1;       // integers <=128: exact in bf16
    ushort2 st;
    st.x = *reinterpret_cast<unsigned short*>(&h0);
    st.y = *reinterpret_cast<unsigned short*>(&h1);
    // swizzle: ushort idx (2*lane) ^ ((row&7)<<3)  ->  ushort2 idx lane ^ ((row&7)<<2)
    reinterpret_cast<ushort2*>(q + (size_t)row * 128)[lane ^ ((row & 7) << 2)] = st;
    if (lane == 0) s1[row] = scale;
}

// ---------------- inputs2: per-k-row (N=2048) amax -> s2 ----------------
__global__ __launch_bounds__(256) void amax_rows2048(const float* __restrict__ x,
                                                     float* __restrict__ s2) {
    int row = blockIdx.x;                          // B*K = 4096 rows
    const float4* xr = reinterpret_cast<const float4*>(x) + (size_t)row * 512;
    int t = threadIdx.x;
    float4 v0 = xr[t], v1 = xr[t + 256];
    float a = fmaxf(fmaxf(fmaxf(fabsf(v0.x), fabsf(v0.y)), fmaxf(fabsf(v0.z), fabsf(v0.w))),
                    fmaxf(fmaxf(fabsf(v1.x), fabsf(v1.y)), fmaxf(fabsf(v1.z), fabsf(v1.w))));
#pragma unroll
    for (int m = 32; m; m >>= 1) a = fmaxf(a, __shfl_xor(a, m));
    __shared__ float red[4];
    if ((t & 63) == 0) red[t >> 6] = a;
    __syncthreads();
    if (t == 0) {
        float m0 = fmaxf(fmaxf(red[0], red[1]), fmaxf(red[2], red[3]));
        s2[row] = fmaxf(m0, EPSQ) / QMAXF;
    }
}

// ---------------- inputs2: dequantize + transpose to q2t image [b*16+nt][rn][k^swz] ----------------
__global__ __launch_bounds__(256) void quant_transpose(const float* __restrict__ x,
                                                       const float* __restrict__ s2,
                                                       unsigned short* __restrict__ q2t) {
    int b = blockIdx.x >> 5;
    int n0 = (blockIdx.x & 31) * 64;
    __shared__ unsigned short lds[64][136];
    int t = threadIdx.x;
    int rr = t >> 4, cc = t & 15;
#pragma unroll
    for (int p = 0; p < 8; ++p) {
        int k = p * 16 + rr;
        float s = s2[b * 128 + k];
        const float4* src = reinterpret_cast<const float4*>(x + ((size_t)b * 128 + k) * 2048 + n0);
        float4 v = src[cc];
        float f[4] = {v.x, v.y, v.z, v.w};
#pragma unroll
        for (int e = 0; e < 4; ++e) {
            float iq = fminf(fmaxf(rintf(f[e] / s), -128.f), 127.f);
            __bf16 h = (__bf16)(iq * s);
            lds[cc * 4 + e][k] = *reinterpret_cast<unsigned short*>(&h);
        }
    }
    __syncthreads();
    int nl = t >> 2, seg = t & 3;
    int sw = nl & 7;                               // (n0+nl)&7 == nl&7 (n0 multiple of 64)
    uint4* dstrow = reinterpret_cast<uint4*>(q2t + ((size_t)b * 2048 + n0 + nl) * 128);
#pragma unroll
    for (int j = 0; j < 4; ++j)
        dstrow[(seg * 4 + j) ^ sw] = *reinterpret_cast<const uint4*>(&lds[nl][seg * 32 + j * 8]);
}

// ---------------- fused GEMM: one block per (b, mt) 128x2048 row-panel.
// Sweep 1 (nt 0..15): LDS double-buffered B, MFMA, deferred per-lane amax. (barrier'd)
// Boundary: reduce amax -> osc.
// Sweep 2 (nt 0..15): B fragments DIRECT FROM GLOBAL (L2-hot), recompute, quantize,
// plain float4 stores. NO LDS, NO barriers, NO waits -> stores stream at full BW. ----------------
__global__ __launch_bounds__(256, 2) void gemm_fused(const unsigned short* __restrict__ qa,
                                                     const unsigned short* __restrict__ qbt,
                                                     const float* __restrict__ s1,
                                                     float* __restrict__ out) {
    int id = blockIdx.x;
    int nid = (id & 7) * 64 + (id >> 3);           // batch-grouped XCD mapping (512 % 8 == 0)
    int b = nid >> 4, mt = nid & 15;

    __shared__ unsigned short Bt[2][16384];        // 64 KB: B double-buffer (Bt[1] = A staging first)
    __shared__ float rowAmax[128], sOsc[128], sQs[128], sS1[128];

    int tid = threadIdx.x, wave = tid >> 6, lane = tid & 63;
    if (tid < 128) {
        rowAmax[tid] = 0.f;
        sS1[tid] = s1[b * 2048 + mt * 128 + tid];
    }

    {   // stage A image into Bt[1], B0 image into Bt[0]
        const char* Ag = (const char*)(qa + (size_t)(b * 16 + mt) * 16384);
        const char* Bg = (const char*)(qbt + (size_t)(b * 16) * 16384);
        char* lA = (char*)&Bt[1][0];
        char* lB = (char*)&Bt[0][0];
#pragma unroll
        for (int i = 0; i < 8; ++i) {
            int off = i * 4096 + wave * 1024;      // wave-uniform LDS dest; HW adds lane*16
            __builtin_amdgcn_global_load_lds(
                (const __attribute__((address_space(1))) uint32_t*)(Ag + off + lane * 16),
                (__attribute__((address_space(3))) uint32_t*)(lA + off), 16, 0, 0);
            __builtin_amdgcn_global_load_lds(
                (const __attribute__((address_space(1))) uint32_t*)(Bg + off + lane * 16),
                (__attribute__((address_space(3))) uint32_t*)(lB + off), 16, 0, 0);
        }
    }
    __syncthreads();

    int wm = wave >> 1, wn = wave & 1;             // 2x2 waves, 64x64 output each
    int lr = lane & 15, lg = lane >> 4;
    int swz = (lr & 7) << 3;                       // read-side XOR swizzle (matches image layout)

    // hoist A fragments to registers: afr[ks][mi] (64 VGPR), A never read from LDS again
    bf16x8 afr[4][4];
#pragma unroll
    for (int ks = 0; ks < 4; ++ks)
#pragma unroll
        for (int mi = 0; mi < 4; ++mi)
            afr[ks][mi] = *reinterpret_cast<const bf16x8*>(
                &Bt[1][(wm * 64 + mi * 16 + lr) * 128 + ((ks * 32 + lg * 8) ^ swz)]);
    __syncthreads();                               // A captured; Bt[1] becomes B buffer

    size_t ob = (size_t)b * 2048 * 2048;
    float rmax[4] = {0.f, 0.f, 0.f, 0.f};          // per-lane running |C| max, one per mi

    // ================= sweep 1: amax (LDS double-buffered, barrier'd) =================
    for (int it = 0; it < 16; ++it) {
        int cur = it & 1;
        if (it < 15) {                             // prefetch next B tile
            const char* Bg = (const char*)(qbt + (size_t)(b * 16 + it + 1) * 16384);
            char* lB = (char*)&Bt[cur ^ 1][0];
#pragma unroll
            for (int i = 0; i < 8; ++i) {
                int off = i * 4096 + wave * 1024;
                __builtin_amdgcn_global_load_lds(
                    (const __attribute__((address_space(1))) uint32_t*)(Bg + off + lane * 16),
                    (__attribute__((address_space(3))) uint32_t*)(lB + off), 16, 0, 0);
            }
        }

        f32x4 acc[4][4];
#pragma unroll
        for (int mi = 0; mi < 4; ++mi)
#pragma unroll
            for (int ni = 0; ni < 4; ++ni) {
                f32x4 z = {0.f, 0.f, 0.f, 0.f};
                acc[mi][ni] = z;
            }
#pragma unroll
        for (int ks = 0; ks < 4; ++ks) {
            int kb = (ks * 32 + lg * 8) ^ swz;
            bf16x8 bfr[4];
#pragma unroll
            for (int ni = 0; ni < 4; ++ni)
                bfr[ni] = *reinterpret_cast<const bf16x8*>(&Bt[cur][(wn * 64 + ni * 16 + lr) * 128 + kb]);
            // SWAPPED operands (R10/R12-verified): lane row=lr, cols=lg*4+r per ni
#pragma unroll
            for (int mi = 0; mi < 4; ++mi)
#pragma unroll
                for (int ni = 0; ni < 4; ++ni)
                    acc[mi][ni] = __builtin_amdgcn_mfma_f32_16x16x32_bf16(bfr[ni], afr[ks][mi], acc[mi][ni], 0, 0, 0);
        }
        // deferred amax: per-lane running max only
#pragma unroll
        for (int mi = 0; mi < 4; ++mi)
#pragma unroll
            for (int ni = 0; ni < 4; ++ni)
#pragma unroll
                for (int r = 0; r < 4; ++r)
                    rmax[mi] = fmaxf(rmax[mi], fabsf(acc[mi][ni][r]));
        __syncthreads();                           // prefetch landed; reads of Bt[cur] done
    }

    // ================= boundary: reduce amax -> per-row osc =================
#pragma unroll
    for (int mi = 0; mi < 4; ++mi) {
        float v = rmax[mi];
        v = fmaxf(v, __shfl_xor(v, 16));
        v = fmaxf(v, __shfl_xor(v, 32));
        if (lg == 0) {                             // raw amax >=0: uint compare == float compare
            int row = wm * 64 + mi * 16 + lr;
            atomicMax(reinterpret_cast<unsigned*>(&rowAmax[row]), __float_as_uint(v));
        }
    }
    __syncthreads();
    if (tid < 128) {
        float am = rowAmax[tid] * sS1[tid];
        float osc = fmaxf(am, EPSQ) / QMAXF;
        sOsc[tid] = osc;
        sQs[tid] = sS1[tid] / osc;                 // folded (raw_acc * s1) / osc
    }
    __syncthreads();

    // ================= sweep 2: quantize+store, FREE-RUNNING (no LDS, no barriers) =================
    const unsigned short* Bimg = qbt + (size_t)b * 16 * 16384;
    for (int nt = 0; nt < 16; ++nt) {
        f32x4 acc[4][4];
#pragma unroll
        for (int mi = 0; mi < 4; ++mi)
#pragma unroll
            for (int ni = 0; ni < 4; ++ni) {
                f32x4 z = {0.f, 0.f, 0.f, 0.f};
                acc[mi][ni] = z;
            }
#pragma unroll
        for (int ks = 0; ks < 4; ++ks) {
            int kb = (ks * 32 + lg * 8) ^ swz;
            bf16x8 bfr[4];
#pragma unroll
            for (int ni = 0; ni < 4; ++ni)
                bfr[ni] = *reinterpret_cast<const bf16x8*>(
                    &Bimg[(size_t)(nt * 128 + wn * 64 + ni * 16 + lr) * 128 + kb]);  // L2-hot
#pragma unroll
            for (int mi = 0; mi < 4; ++mi)
#pragma unroll
                for (int ni = 0; ni < 4; ++ni)
                    acc[mi][ni] = __builtin_amdgcn_mfma_f32_16x16x32_bf16(bfr[ni], afr[ks][mi], acc[mi][ni], 0, 0, 0);
        }
#pragma unroll
        for (int mi = 0; mi < 4; ++mi) {
            int row = wm * 64 + mi * 16 + lr;
            float qs = sQs[row], osc = sOsc[row];
            size_t rowoff = ob + (size_t)(mt * 128 + row) * 2048 + nt * 128 + wn * 64 + lg * 4;
#pragma unroll
            for (int ni = 0; ni < 4; ++ni) {
                f32x4 qv;
                qv[0] = fminf(fmaxf(rintf(acc[mi][ni][0] * qs), -128.f), 127.f) * osc;
                qv[1] = fminf(fmaxf(rintf(acc[mi][ni][1] * qs), -128.f), 127.f) * osc;
                qv[2] = fminf(fmaxf(rintf(acc[mi][ni][2] * qs), -128.f), 127.f) * osc;
                qv[3] = fminf(fmaxf(rintf(acc[mi][ni][3] * qs), -128.f), 127.f) * osc;
                *reinterpret_cast<f32x4*>(&out[rowoff + ni * 16]) = qv;
            }
        }
    }
}

extern "C" void kernel_launch(void* const* d_in, const int* in_sizes, int n_in,
                              void* d_out, int out_size, void* d_ws, size_t ws_size,
                              hipStream_t stream) {
    const float* in1 = (const float*)d_in[0];  // [2,16,2048,128]
    const float* in2 = (const float*)d_in[1];  // [2,16,128,2048]
    char* ws = (char*)d_ws;
    unsigned short* q1  = (unsigned short*)(ws + OFF_Q1);
    unsigned short* q2t = (unsigned short*)(ws + OFF_Q2T);
    float* s1   = (float*)(ws + OFF_S1);
    float* s2   = (float*)(ws + OFF_S2);
    float* out  = (float*)d_out;

    quant_rows128 <<<BB * MM / 4, 256, 0, stream>>>(in1, q1, s1);
    amax_rows2048 <<<BB * KK,     256, 0, stream>>>(in2, s2);
    quant_transpose<<<BB * (NN / 64), 256, 0, stream>>>(in2, s2, q2t);
    gemm_fused    <<<BB * 16,     256, 0, stream>>>(q1, q2t, s1, out);
}

// Round 16
// 191.457 us; speedup vs baseline: 1.1580x; 1.1531x over previous
//
#include <hip/hip_runtime.h>
#include <hip/hip_bf16.h>
#include <cstdint>

#define QMAXF 127.0f
#define EPSQ 1e-8f

typedef __bf16 bf16x8 __attribute__((ext_vector_type(8)));
typedef float f32x4 __attribute__((ext_vector_type(4)));

static constexpr int BB = 32;   // 2*16 batch
static constexpr int MM = 2048;
static constexpr int KK = 128;
static constexpr int NN = 2048;

// workspace layout (bytes)
static constexpr size_t OFF_Q1   = 0;                                  // ushort tile-images of A (swizzled)
static constexpr size_t OFF_Q2T  = OFF_Q1  + (size_t)BB*MM*KK*2;       // ushort tile-images of B^T (swizzled)
static constexpr size_t OFF_S1   = OFF_Q2T + (size_t)BB*NN*KK*2;       // float[B*M]
static constexpr size_t OFF_S2   = OFF_S1  + (size_t)BB*MM*4;          // float[B*K]

// ---------------- quantize inputs1: per-row (K=128) amax; store exact-int bf16, K-swizzled ----------------
__global__ __launch_bounds__(256) void quant_rows128(const float* __restrict__ x,
                                                     unsigned short* __restrict__ q,
                                                     float* __restrict__ s1) {
    int wave = threadIdx.x >> 6, lane = threadIdx.x & 63;
    int row = blockIdx.x * 4 + wave;               // 65536 rows
    const float2* xr = reinterpret_cast<const float2*>(x) + (size_t)row * 64;
    float2 v = xr[lane];
    float a = fmaxf(fabsf(v.x), fabsf(v.y));
#pragma unroll
    for (int m = 32; m; m >>= 1) a = fmaxf(a, __shfl_xor(a, m));
    float scale = fmaxf(a, EPSQ) / QMAXF;
    float i0 = fminf(fmaxf(rintf(v.x / scale), -128.f), 127.f);
    float i1 = fminf(fmaxf(rintf(v.y / scale), -128.f), 127.f);
    __bf16 h0 = (__bf16)i0, h1 = (__bf16)i1;       // integers <=128: exact in bf16
    ushort2 st;
    st.x = *reinterpret_cast<unsigned short*>(&h0);
    st.y = *reinterpret_cast<unsigned short*>(&h1);
    // swizzle: ushort idx (2*lane) ^ ((row&7)<<3)  ->  ushort2 idx lane ^ ((row&7)<<2)
    reinterpret_cast<ushort2*>(q + (size_t)row * 128)[lane ^ ((row & 7) << 2)] = st;
    if (lane == 0) s1[row] = scale;
}

// ---------------- inputs2: per-k-row (N=2048) amax -> s2 ----------------
__global__ __launch_bounds__(256) void amax_rows2048(const float* __restrict__ x,
                                                     float* __restrict__ s2) {
    int row = blockIdx.x;                          // B*K = 4096 rows
    const float4* xr = reinterpret_cast<const float4*>(x) + (size_t)row * 512;
    int t = threadIdx.x;
    float4 v0 = xr[t], v1 = xr[t + 256];
    float a = fmaxf(fmaxf(fmaxf(fabsf(v0.x), fabsf(v0.y)), fmaxf(fabsf(v0.z), fabsf(v0.w))),
                    fmaxf(fmaxf(fabsf(v1.x), fabsf(v1.y)), fmaxf(fabsf(v1.z), fabsf(v1.w))));
#pragma unroll
    for (int m = 32; m; m >>= 1) a = fmaxf(a, __shfl_xor(a, m));
    __shared__ float red[4];
    if ((t & 63) == 0) red[t >> 6] = a;
    __syncthreads();
    if (t == 0) {
        float m0 = fmaxf(fmaxf(red[0], red[1]), fmaxf(red[2], red[3]));
        s2[row] = fmaxf(m0, EPSQ) / QMAXF;
    }
}

// ---------------- inputs2: dequantize + transpose to q2t image [b*16+nt][rn][k^swz] ----------------
__global__ __launch_bounds__(256) void quant_transpose(const float* __restrict__ x,
                                                       const float* __restrict__ s2,
                                                       unsigned short* __restrict__ q2t) {
    int b = blockIdx.x >> 5;
    int n0 = (blockIdx.x & 31) * 64;
    __shared__ unsigned short lds[64][136];
    int t = threadIdx.x;
    int rr = t >> 4, cc = t & 15;
#pragma unroll
    for (int p = 0; p < 8; ++p) {
        int k = p * 16 + rr;
        float s = s2[b * 128 + k];
        const float4* src = reinterpret_cast<const float4*>(x + ((size_t)b * 128 + k) * 2048 + n0);
        float4 v = src[cc];
        float f[4] = {v.x, v.y, v.z, v.w};
#pragma unroll
        for (int e = 0; e < 4; ++e) {
            float iq = fminf(fmaxf(rintf(f[e] / s), -128.f), 127.f);
            __bf16 h = (__bf16)(iq * s);
            lds[cc * 4 + e][k] = *reinterpret_cast<unsigned short*>(&h);
        }
    }
    __syncthreads();
    int nl = t >> 2, seg = t & 3;
    int sw = nl & 7;                               // (n0+nl)&7 == nl&7 (n0 multiple of 64)
    uint4* dstrow = reinterpret_cast<uint4*>(q2t + ((size_t)b * 2048 + n0 + nl) * 128);
#pragma unroll
    for (int j = 0; j < 4; ++j)
        dstrow[(seg * 4 + j) ^ sw] = *reinterpret_cast<const uint4*>(&lds[nl][seg * 32 + j * 8]);
}

// ---------------- fused GEMM: one block per (b, mt) 128x2048 row-panel. NO LDS STAGING.
// A frags in registers (prologue). B frags roll through registers: the 4 loads refilling
// bfr[ks] (next tile) issue immediately after the 16 MFMAs consuming bfr[ks] — so ALL
// next-tile loads are OLDER than this tile's stores in the wave's in-order vmcnt queue.
// The MFMA load-wait then never drains stores (the R11-R15 serialization).
// Sweep 1 (nt 0..15): deferred per-lane amax. Sweep 2: quantize + float4 stores. ----------------
__global__ __launch_bounds__(256, 2) void gemm_fused(const unsigned short* __restrict__ qa,
                                                     const unsigned short* __restrict__ qbt,
                                                     const float* __restrict__ s1,
                                                     float* __restrict__ out) {
    int id = blockIdx.x;
    int nid = (id & 7) * 64 + (id >> 3);           // batch-grouped XCD mapping (512 % 8 == 0)
    int b = nid >> 4, mt = nid & 15;

    __shared__ float rowAmax[128], sOsc[128], sQs[128], sS1[128];

    int tid = threadIdx.x, wave = tid >> 6, lane = tid & 63;
    if (tid < 128) {
        rowAmax[tid] = 0.f;
        sS1[tid] = s1[b * 2048 + mt * 128 + tid];
    }

    int wm = wave >> 1, wn = wave & 1;             // 2x2 waves, 64x64 output each
    int lr = lane & 15, lg = lane >> 4;
    int swz = (lr & 7) << 3;                       // XOR swizzle baked into the images

    // A fragments: direct global -> registers (32 KB/block, L3-hot)
    bf16x8 afr[4][4];
    {
        const unsigned short* Ai = qa + (size_t)(b * 16 + mt) * 16384;
#pragma unroll
        for (int ks = 0; ks < 4; ++ks)
#pragma unroll
            for (int mi = 0; mi < 4; ++mi)
                afr[ks][mi] = *reinterpret_cast<const bf16x8*>(
                    &Ai[(wm * 64 + mi * 16 + lr) * 128 + ((ks * 32 + lg * 8) ^ swz)]);
    }

    const unsigned short* Bimg = qbt + (size_t)b * 16 * 16384;
    // per-lane B fragment offset for (nt, ks, ni)
    auto boff = [&](int nt, int ks, int ni) -> size_t {
        return (size_t)(nt * 128 + wn * 64 + ni * 16 + lr) * 128 + ((ks * 32 + lg * 8) ^ swz);
    };

    // rolling B fragment registers: preload tile 0
    bf16x8 bfr[4][4];
#pragma unroll
    for (int ks = 0; ks < 4; ++ks)
#pragma unroll
        for (int ni = 0; ni < 4; ++ni)
            bfr[ks][ni] = *reinterpret_cast<const bf16x8*>(&Bimg[boff(0, ks, ni)]);

    size_t ob = (size_t)b * 2048 * 2048;
    float rmax[4] = {0.f, 0.f, 0.f, 0.f};          // per-lane running |C| max, one per mi

    // ================= sweep 1: amax (no barriers, rolling refill) =================
    for (int nt = 0; nt < 16; ++nt) {
        int nn = (nt + 1) & 15;                    // nt=15 reloads tile 0 for sweep 2
        f32x4 acc[4][4];
#pragma unroll
        for (int mi = 0; mi < 4; ++mi)
#pragma unroll
            for (int ni = 0; ni < 4; ++ni) {
                f32x4 z = {0.f, 0.f, 0.f, 0.f};
                acc[mi][ni] = z;
            }
#pragma unroll
        for (int ks = 0; ks < 4; ++ks) {
            // SWAPPED operands (R10/R12-verified): lane row=lr, cols=lg*4+r per ni
#pragma unroll
            for (int mi = 0; mi < 4; ++mi)
#pragma unroll
                for (int ni = 0; ni < 4; ++ni)
                    acc[mi][ni] = __builtin_amdgcn_mfma_f32_16x16x32_bf16(bfr[ks][ni], afr[ks][mi], acc[mi][ni], 0, 0, 0);
            // refill bfr[ks] with next tile right after last use (loads precede any stores)
#pragma unroll
            for (int ni = 0; ni < 4; ++ni)
                bfr[ks][ni] = *reinterpret_cast<const bf16x8*>(&Bimg[boff(nn, ks, ni)]);
        }
#pragma unroll
        for (int mi = 0; mi < 4; ++mi)
#pragma unroll
            for (int ni = 0; ni < 4; ++ni)
#pragma unroll
                for (int r = 0; r < 4; ++r)
                    rmax[mi] = fmaxf(rmax[mi], fabsf(acc[mi][ni][r]));
    }

    // ================= boundary: reduce amax -> per-row osc =================
#pragma unroll
    for (int mi = 0; mi < 4; ++mi) {
        float v = rmax[mi];
        v = fmaxf(v, __shfl_xor(v, 16));
        v = fmaxf(v, __shfl_xor(v, 32));
        if (lg == 0) {                             // raw amax >=0: uint compare == float compare
            int row = wm * 64 + mi * 16 + lr;
            atomicMax(reinterpret_cast<unsigned*>(&rowAmax[row]), __float_as_uint(v));
        }
    }
    __syncthreads();
    if (tid < 128) {
        float am = rowAmax[tid] * sS1[tid];
        float osc = fmaxf(am, EPSQ) / QMAXF;
        sOsc[tid] = osc;
        sQs[tid] = sS1[tid] / osc;                 // folded (raw_acc * s1) / osc
    }
    __syncthreads();                               // bfr holds tile 0 again (rolled at nt=15)

    // ================= sweep 2: quantize + store (no barriers, loads-before-stores) =================
    for (int nt = 0; nt < 16; ++nt) {
        int nn = (nt + 1) & 15;
        f32x4 acc[4][4];
#pragma unroll
        for (int mi = 0; mi < 4; ++mi)
#pragma unroll
            for (int ni = 0; ni < 4; ++ni) {
                f32x4 z = {0.f, 0.f, 0.f, 0.f};
                acc[mi][ni] = z;
            }
#pragma unroll
        for (int ks = 0; ks < 4; ++ks) {
#pragma unroll
            for (int mi = 0; mi < 4; ++mi)
#pragma unroll
                for (int ni = 0; ni < 4; ++ni)
                    acc[mi][ni] = __builtin_amdgcn_mfma_f32_16x16x32_bf16(bfr[ks][ni], afr[ks][mi], acc[mi][ni], 0, 0, 0);
#pragma unroll
            for (int ni = 0; ni < 4; ++ni)
                bfr[ks][ni] = *reinterpret_cast<const bf16x8*>(&Bimg[boff(nn, ks, ni)]);
        }
        // stores are YOUNGER than all 16 next-tile loads -> next iter's MFMA load-wait
        // (vmcnt counts in-order) never waits on these stores; they drain in background.
#pragma unroll
        for (int mi = 0; mi < 4; ++mi) {
            int row = wm * 64 + mi * 16 + lr;
            float qs = sQs[row], osc = sOsc[row];
            size_t rowoff = ob + (size_t)(mt * 128 + row) * 2048 + nt * 128 + wn * 64 + lg * 4;
#pragma unroll
            for (int ni = 0; ni < 4; ++ni) {
                f32x4 qv;
                qv[0] = fminf(fmaxf(rintf(acc[mi][ni][0] * qs), -128.f), 127.f) * osc;
                qv[1] = fminf(fmaxf(rintf(acc[mi][ni][1] * qs), -128.f), 127.f) * osc;
                qv[2] = fminf(fmaxf(rintf(acc[mi][ni][2] * qs), -128.f), 127.f) * osc;
                qv[3] = fminf(fmaxf(rintf(acc[mi][ni][3] * qs), -128.f), 127.f) * osc;
                *reinterpret_cast<f32x4*>(&out[rowoff + ni * 16]) = qv;
            }
        }
    }
}

extern "C" void kernel_launch(void* const* d_in, const int* in_sizes, int n_in,
                              void* d_out, int out_size, void* d_ws, size_t ws_size,
                              hipStream_t stream) {
    const float* in1 = (const float*)d_in[0];  // [2,16,2048,128]
    const float* in2 = (const float*)d_in[1];  // [2,16,128,2048]
    char* ws = (char*)d_ws;
    unsigned short* q1  = (unsigned short*)(ws + OFF_Q1);
    unsigned short* q2t = (unsigned short*)(ws + OFF_Q2T);
    float* s1   = (float*)(ws + OFF_S1);
    float* s2   = (float*)(ws + OFF_S2);
    float* out  = (float*)d_out;

    quant_rows128 <<<BB * MM / 4, 256, 0, stream>>>(in1, q1, s1);
    amax_rows2048 <<<BB * KK,     256, 0, stream>>>(in2, s2);
    quant_transpose<<<BB * (NN / 64), 256, 0, stream>>>(in2, s2, q2t);
    gemm_fused    <<<BB * 16,     256, 0, stream>>>(q1, q2t, s1, out);
}